// Round 3
// baseline (282.582 us; speedup 1.0000x reference)
//
#include <hip/hip_runtime.h>
#include <hip/hip_bf16.h>

typedef __attribute__((ext_vector_type(8))) short bf16x8;
typedef __attribute__((ext_vector_type(4))) float f32x4;
typedef __attribute__((ext_vector_type(16))) float f32x16;

namespace {

constexpr int kT = 16;
constexpr int kC = 256;
constexpr int kHW = 1024;

__device__ __forceinline__ unsigned short f2bf(float f) {
  unsigned int x;
  __builtin_memcpy(&x, &f, 4);
  x += 0x7fff + ((x >> 16) & 1);  // round-to-nearest-even
  return (unsigned short)(x >> 16);
}
__device__ __forceinline__ unsigned int pack2(float a, float b) {
  return (unsigned int)f2bf(a) | ((unsigned int)f2bf(b) << 16);
}

// ============================ prep kernel ============================
// blocks < 4096: x (b,t,c,hw) fp32 -> xT (b,hw,t,c) bf16  (r3-proven body)
// blocks >= 4096: weight reorder+convert -> wAll bf16 [1024 rows x 256]:
//   rows g*32..g*32+31 for g<24: (head=g/3, sel=g%3) rows of wqkv;
//   g in 24..31: wout rows (g-24)*32...   (linear layout, round-0 proven)
__global__ __launch_bounds__(256) void prep(const float* __restrict__ x,
                                            const float* __restrict__ wqkv,
                                            const float* __restrict__ wout,
                                            unsigned short* __restrict__ xT,
                                            unsigned short* __restrict__ wAll) {
  __shared__ unsigned short ts[64 * 72];
  const int bx = blockIdx.x;
  const int tid = threadIdx.x;
  if (bx < 4096) {
    const int cc = bx & 3, hc = (bx >> 2) & 15, t = (bx >> 6) & 15, b = bx >> 10;
    const int c0 = cc * 64, hw0 = hc * 64;
    {
      const int ci = tid >> 2, j = tid & 3;
      const float* xrow = x + (((size_t)(b * 16 + t) * 256 + c0 + ci) * 1024) + hw0;
#pragma unroll
      for (int u = 0; u < 4; ++u) {
        const int chunk = j + u * 4;
        const float4 v = *(const float4*)(xrow + chunk * 4);
        const int hwl = chunk * 4;
        ts[(hwl + 0) * 72 + ci] = f2bf(v.x);
        ts[(hwl + 1) * 72 + ci] = f2bf(v.y);
        ts[(hwl + 2) * 72 + ci] = f2bf(v.z);
        ts[(hwl + 3) * 72 + ci] = f2bf(v.w);
      }
    }
    __syncthreads();
    {
      const int hwp = tid >> 2, jp = tid & 3;
      const uint4 a = *(const uint4*)&ts[hwp * 72 + jp * 16];
      const uint4 bq = *(const uint4*)&ts[hwp * 72 + jp * 16 + 8];
      unsigned short* dst =
          xT + ((size_t)((b * 1024 + hw0 + hwp) * 16 + t) * 256) + c0 + jp * 16;
      *(uint4*)dst = a;
      *(uint4*)(dst + 8) = bq;
    }
  } else {
    const int g = bx - 4096;            // 0..31
    const int row_l = tid >> 3;         // 0..31
    const int seg = tid & 7;            // 8 segs x 32 elems
    const float* src;
    int srow;
    if (g < 24) { src = wqkv; srow = (g % 3) * 256 + (g / 3) * 32 + row_l; }
    else        { src = wout; srow = (g - 24) * 32 + row_l; }
    const float* s = src + (size_t)srow * 256 + seg * 32;
    unsigned short* d = wAll + ((size_t)(g * 32 + row_l)) * 256 + seg * 32;
#pragma unroll
    for (int u = 0; u < 8; ++u) {
      const float4 v = *(const float4*)(s + u * 4);
      uint2 p;
      p.x = pack2(v.x, v.y);
      p.y = pack2(v.z, v.w);
      *(uint2*)(d + u * 4) = p;
    }
  }
}

// ============================ main kernel ============================
// v4: 256 thr = 4 waves; wave handles 2 consecutive hw sites via m=32 MFMA;
// block = 8 consecutive hw; grid 512 => 2 blocks/CU (round-2 body was
// 1 block/CU with everything idle: occupancy 21.7%, MfmaUtil 13%).
// Body byte-identical to round-2's proven loop (reg-staged dbuf, 264 stride,
// 2 barriers/tile, fully unrolled heads). Bias preloaded to registers so the
// post-barrier acc init doesn't wait on a global load. Bijective XCD swizzle
// keeps the two half-line writers of each output cache line on one XCD.
constexpr int kWBStride = 264;                 // 256 + 8 pad (elems)
constexpr int kWBTile = 32 * kWBStride;        // 8448 elems
constexpr int kWB = 2 * kWBTile;               // 16896 elems
constexpr int kSite = 1824;                    // per-wave: q640(s40)|k640(s40,P s24)|vt512(s16)|pad
constexpr int kSmem = kWB + 4 * kSite;         // 24192 elems = 48384 B
static_assert(kSmem * 2 <= 65536, "LDS budget");
static_assert(512 * 9 * 4 <= kSmem * 2, "fbuf fits");

__global__ __launch_bounds__(256, 2) void attn_main(
    const unsigned short* __restrict__ xT,    // (4,1024,16,256) bf16
    const float* __restrict__ rel,            // (8,16,16) fp32
    const unsigned short* __restrict__ wAll,  // (1024,256) bf16 reordered
    const float* __restrict__ bqkv,           // (768,) fp32
    const float* __restrict__ bout,           // (256,) fp32
    float* __restrict__ out) {                // (4,16,256,32,32) fp32
  __shared__ __align__(16) unsigned short smem[kSmem];
  const int tid = threadIdx.x;
  const int lane = tid & 63;
  const int wave = tid >> 6;   // 0..3
  const int quad = lane >> 4;
  const int lrow = lane & 15;
  const int half = lane >> 5;
  const int n32 = lane & 31;
  // bijective XCD-contiguous swizzle (512 % 8 == 0): XCD x owns vids [64x,64x+64)
  const int bid = blockIdx.x;
  const int vid = (bid & 7) * 64 + (bid >> 3);
  const int b = vid >> 7;
  const int hw0 = (vid & 127) * 8;
  const int site0 = hw0 + wave * 2;

  // ---- A-frags of X, m=32 = 2 sites stacked (m=lane&31: s=m>>4, t=m&15) ----
  bf16x8 ax[16];
  {
    const unsigned short* xs =
        xT + (((size_t)(b * 1024 + site0 + (n32 >> 4))) << 12) + lrow * 256;
#pragma unroll
    for (int ks = 0; ks < 16; ++ks)
      ax[ks] = *(const bf16x8*)(xs + ks * 16 + half * 8);
  }

  // ---- bias preload: 24 regs, statically indexed (heads unrolled) ----
  float bq0[8], bk0[8], bv0[8];
#pragma unroll
  for (int h = 0; h < 8; ++h) {
    bq0[h] = bqkv[h * 32 + n32];
    bk0[h] = bqkv[256 + h * 32 + n32];
    bv0[h] = bqkv[512 + h * 32 + n32];
  }

  unsigned short* qb = smem + kWB + wave * kSite;
  unsigned short* kb = qb + 640;
  unsigned short* vt = qb + 1280;  // stride 16, [d][j]

  // staging: 256 thr x 64 B = one 32x256 tile; thread owns row tid>>3,
  // 32-elem segment (tid&7)*32.
  const int stageDst = (tid >> 3) * kWBStride + (tid & 7) * 32;
  const int stageSrcOff = (tid >> 3) * 256 + (tid & 7) * 32;

  // prefetch stage tile 0 (4 x uint4 = 64 B)
  uint4 pr[4];
  {
    const unsigned short* sp = wAll + stageSrcOff;
#pragma unroll
    for (int i = 0; i < 4; ++i) pr[i] = *(const uint4*)(sp + i * 8);
  }

  const f32x4 zero4 = {0.f, 0.f, 0.f, 0.f};
  const float scale = 0.17677669529663687f;  // 32^-0.5
  bf16x8 ao[2][8];

  // staged QKV tile: stage g from regs, prefetch g+1, 16-kstep 32x32x16 MFMA
  auto qkv_tile = [&](int g, float bias) -> f32x16 {
    __syncthreads();  // WB[g&1] free (consumers of g-2 done)
    unsigned short* WBc = smem + (g & 1) * kWBTile;
#pragma unroll
    for (int i = 0; i < 4; ++i) *(uint4*)(WBc + stageDst + i * 8) = pr[i];
    {
      const unsigned short* sp = wAll + (size_t)(g + 1) * 32 * 256 + stageSrcOff;
#pragma unroll
      for (int i = 0; i < 4; ++i) pr[i] = *(const uint4*)(sp + i * 8);
    }
    __syncthreads();  // WB[g&1] ready
    f32x16 acc;
#pragma unroll
    for (int i = 0; i < 16; ++i) acc[i] = bias;
    const unsigned short* br = WBc + n32 * kWBStride + half * 8;
#pragma unroll
    for (int ks = 0; ks < 16; ++ks) {
      const bf16x8 bf = *(const bf16x8*)(br + ks * 16);
      acc = __builtin_amdgcn_mfma_f32_32x32x16_bf16(ax[ks], bf, acc, 0, 0, 0);
    }
    return acc;
  };

  // one head, h is a compile-time literal at each call site
  auto head_body = [&](int h) {
    const f32x16 qacc = qkv_tile(h * 3 + 0, bq0[h]);
    const f32x16 kacc = qkv_tile(h * 3 + 1, bk0[h]);
    const f32x16 vacc = qkv_tile(h * 3 + 2, bv0[h]);
    float rl[4];
#pragma unroll
    for (int r = 0; r < 4; ++r) rl[r] = rel[h * 256 + (quad * 4 + r) * 16 + lrow];

#pragma unroll
    for (int s = 0; s < 2; ++s) {
      // C/D 32x32: reg=8s+rr -> row=16s+t, t=(rr&3)+8*(rr>>2)+4*half, col=n32
#pragma unroll
      for (int rr = 0; rr < 8; ++rr) {
        const int t = (rr & 3) + 8 * (rr >> 2) + 4 * half;
        qb[t * 40 + n32] = f2bf(qacc[8 * s + rr]);
        kb[t * 40 + n32] = f2bf(kacc[8 * s + rr]);
      }
#pragma unroll
      for (int rp = 0; rp < 4; ++rp) {  // vT[d][j], paired t writes (b32)
        const int rr = rp * 2;
        const int t = (rr & 3) + 8 * (rr >> 2) + 4 * half;
        *(unsigned int*)&vt[n32 * 16 + t] =
            pack2(vacc[8 * s + rr], vacc[8 * s + rr + 1]);
      }
      // sim (16x16x32): A=q[m=t][k=d], B[k=d][n=j]=k[j][d]
      const bf16x8 qf = *(const bf16x8*)(qb + lrow * 40 + quad * 8);
      const bf16x8 kf = *(const bf16x8*)(kb + lrow * 40 + quad * 8);
      const f32x4 sim = __builtin_amdgcn_mfma_f32_16x16x32_bf16(qf, kf, zero4, 0, 0, 0);
      float p[4], inv[4];
#pragma unroll
      for (int r = 0; r < 4; ++r) {
        const float v = sim[r] * scale + rl[r];
        float m = v;
        for (int off = 8; off; off >>= 1) m = fmaxf(m, __shfl_xor(m, off));
        const float e = __expf(v - m);
        float sum = e;
        for (int off = 8; off; off >>= 1) sum += __shfl_xor(sum, off);
        p[r] = e;
        inv[r] = 1.0f / sum;
      }
      unsigned short* pb = kb;  // P overlays k (dead), stride 24
#pragma unroll
      for (int r = 0; r < 4; ++r) pb[(quad * 4 + r) * 24 + lrow] = f2bf(p[r]);
      bf16x8 pf, vf0, vf1;
      if (quad < 2) {
        pf = *(const bf16x8*)(pb + lrow * 24 + quad * 8);
        vf0 = *(const bf16x8*)(vt + lrow * 16 + quad * 8);
        vf1 = *(const bf16x8*)(vt + (16 + lrow) * 16 + quad * 8);
      } else {
#pragma unroll
        for (int j = 0; j < 8; ++j) { pf[j] = 0; vf0[j] = 0; vf1[j] = 0; }
      }
      const f32x4 o0 = __builtin_amdgcn_mfma_f32_16x16x32_bf16(pf, vf0, zero4, 0, 0, 0);
      const f32x4 o1 = __builtin_amdgcn_mfma_f32_16x16x32_bf16(pf, vf1, zero4, 0, 0, 0);
#pragma unroll
      for (int r = 0; r < 4; ++r) {  // O bounce into qb (dead) -> A-layout
        const int t = quad * 4 + r;
        qb[t * 40 + lrow] = f2bf(o0[r] * inv[r]);
        qb[t * 40 + 16 + lrow] = f2bf(o1[r] * inv[r]);
      }
      ao[s][h] = *(const bf16x8*)(qb + lrow * 40 + quad * 8);
    }
  };

  // fully unrolled heads: literal h -> ao[][] statically indexed (registers)
  head_body(0);
  head_body(1);
  head_body(2);
  head_body(3);
  head_body(4);
  head_body(5);
  head_body(6);
  head_body(7);

  // ---- epilogue: y = O @ wout^T + bout; coalesced stores via fp32 LDS bounce ----
  __syncthreads();  // sitebufs/WB dead; fbuf overlays smem
  float* fbuf = (float*)smem;  // [t*32+c_l]*9 + hw_l  (512 lines x 9)
  float* ob = out + ((size_t)b << 22);
#pragma unroll 1
  for (int cc = 0; cc < 8; ++cc) {
#pragma unroll
    for (int sub = 0; sub < 2; ++sub) {
      const int c = cc * 32 + sub * 16 + lrow;
      const float bias = bout[c];
      f32x4 y0 = {bias, bias, bias, bias};
      f32x4 y1 = {bias, bias, bias, bias};
#pragma unroll
      for (int ks = 0; ks < 8; ++ks) {
        const bf16x8 wf =
            *(const bf16x8*)(wAll + (size_t)(768 + c) * 256 + ks * 32 + quad * 8);
        y0 = __builtin_amdgcn_mfma_f32_16x16x32_bf16(ao[0][ks], wf, y0, 0, 0, 0);
        y1 = __builtin_amdgcn_mfma_f32_16x16x32_bf16(ao[1][ks], wf, y1, 0, 0, 0);
      }
#pragma unroll
      for (int r = 0; r < 4; ++r) {
        const int t = quad * 4 + r;
        const int L = (t * 32 + sub * 16 + lrow) * 9 + wave * 2;
        fbuf[L] = y0[r];
        fbuf[L + 1] = y1[r];
      }
    }
    __syncthreads();
#pragma unroll
    for (int q2 = 0; q2 < 2; ++q2) {
      const int L = tid + q2 * 256;
      const int t = L >> 5, cl = L & 31;
      float v[8];
#pragma unroll
      for (int i = 0; i < 8; ++i) v[i] = fbuf[L * 9 + i];
      float* dst = ob + ((size_t)(t * 256 + cc * 32 + cl)) * 1024 + hw0;
      float4 st0, st1;
      st0.x = v[0]; st0.y = v[1]; st0.z = v[2]; st0.w = v[3];
      st1.x = v[4]; st1.y = v[5]; st1.z = v[6]; st1.w = v[7];
      *(float4*)dst = st0;
      *(float4*)(dst + 4) = st1;
    }
    __syncthreads();
  }
}

// ============================ fallback (round-2, passed) ============================
constexpr int kHWT = 4;
constexpr int kXsTStride = kC * kHWT + 8;
constexpr int kXSize = kT * kXsTStride;
constexpr int kWsOff = kXSize;
constexpr int kWsStride = 264;
constexpr int kWsSize = 32 * kWsStride;
constexpr int kQbOff = kWsOff + kWsSize;
constexpr int kQbWave = 1792;
constexpr int kLdsElems = kQbOff + 4 * kQbWave;

__global__ __launch_bounds__(256, 2) void fused_temporal_attn(
    const float* __restrict__ x, const float* __restrict__ rel,
    const float* __restrict__ wqkv, const float* __restrict__ bqkv,
    const float* __restrict__ wout, const float* __restrict__ bout,
    float* __restrict__ out) {
  __shared__ __align__(16) unsigned short smem[kLdsElems];
  const int tid = threadIdx.x;
  const int lane = tid & 63;
  const int wave = tid >> 6;
  const int quad = lane >> 4;
  const int lrow = lane & 15;
  const int b = blockIdx.x >> 8;
  const int tile = blockIdx.x & 255;
  const int hw0 = tile * kHWT;
  {
    const float* xb = x + (size_t)b * kT * kC * kHW + hw0;
#pragma unroll
    for (int it = 0; it < 16; ++it) {
      int idx = it * 256 + tid;
      int t = idx >> 8, c = idx & 255;
      const float4 v = *(const float4*)(xb + (size_t)(t * kC + c) * kHW);
      uint2 p;
      p.x = pack2(v.x, v.y);
      p.y = pack2(v.z, v.w);
      *(uint2*)&smem[t * kXsTStride + c * kHWT] = p;
    }
  }
  __syncthreads();
  bf16x8 ax[8];
#pragma unroll
  for (int ks = 0; ks < 8; ++ks) {
    bf16x8 f;
#pragma unroll
    for (int j = 0; j < 8; ++j) {
      int c = ks * 32 + quad * 8 + j;
      f[j] = (short)smem[lrow * kXsTStride + c * kHWT + wave];
    }
    ax[ks] = f;
  }
  unsigned short* qb = &smem[kQbOff + wave * kQbWave];
  unsigned short* kbuf = qb + 512;
  unsigned short* vtb = qb + 1024;
  unsigned short* pb = qb + 1536;
  const f32x4 zero4 = {0.f, 0.f, 0.f, 0.f};
  bf16x8 ao[8];
  for (int head = 0; head < 8; ++head) {
    for (int sel = 0; sel < 3; ++sel) {
      __syncthreads();
      {
        const float* wbp = wqkv + (size_t)(sel * 256 + head * 32) * kC;
#pragma unroll
        for (int i = 0; i < 8; ++i) {
          int seg = i * 256 + tid;
          int d = seg >> 6, s = seg & 63;
          const float4 v = *(const float4*)(wbp + d * kC + s * 4);
          uint2 p;
          p.x = pack2(v.x, v.y);
          p.y = pack2(v.z, v.w);
          *(uint2*)&smem[kWsOff + d * kWsStride + s * 4] = p;
        }
      }
      __syncthreads();
      float bias0 = bqkv[sel * 256 + head * 32 + lrow];
      float bias1 = bqkv[sel * 256 + head * 32 + 16 + lrow];
      f32x4 acc0 = {bias0, bias0, bias0, bias0};
      f32x4 acc1 = {bias1, bias1, bias1, bias1};
#pragma unroll
      for (int ks = 0; ks < 8; ++ks) {
        bf16x8 b0 = *(const bf16x8*)&smem[kWsOff + lrow * kWsStride + ks * 32 + quad * 8];
        bf16x8 b1 = *(const bf16x8*)&smem[kWsOff + (16 + lrow) * kWsStride + ks * 32 + quad * 8];
        acc0 = __builtin_amdgcn_mfma_f32_16x16x32_bf16(ax[ks], b0, acc0, 0, 0, 0);
        acc1 = __builtin_amdgcn_mfma_f32_16x16x32_bf16(ax[ks], b1, acc1, 0, 0, 0);
      }
      if (sel < 2) {
        unsigned short* dst = sel ? kbuf : qb;
#pragma unroll
        for (int r = 0; r < 4; ++r) {
          int row = quad * 4 + r;
          dst[row * 32 + lrow] = f2bf(acc0[r]);
          dst[row * 32 + 16 + lrow] = f2bf(acc1[r]);
        }
      } else {
#pragma unroll
        for (int r = 0; r < 4; ++r) {
          int row = quad * 4 + r;
          vtb[lrow * 16 + row] = f2bf(acc0[r]);
          vtb[(16 + lrow) * 16 + row] = f2bf(acc1[r]);
        }
      }
    }
    bf16x8 qf = *(const bf16x8*)&qb[lrow * 32 + quad * 8];
    bf16x8 kf = *(const bf16x8*)&kbuf[lrow * 32 + quad * 8];
    f32x4 sim = __builtin_amdgcn_mfma_f32_16x16x32_bf16(qf, kf, zero4, 0, 0, 0);
    const float scale = 0.17677669529663687f;
    float p[4], rsum[4];
#pragma unroll
    for (int r = 0; r < 4; ++r) {
      int i = quad * 4 + r;
      float v = sim[r] * scale + rel[head * 256 + i * 16 + lrow];
      float m = v;
      for (int off = 8; off; off >>= 1) m = fmaxf(m, __shfl_xor(m, off));
      float e = __expf(v - m);
      float s = e;
      for (int off = 8; off; off >>= 1) s += __shfl_xor(s, off);
      p[r] = e;
      rsum[r] = s;
    }
#pragma unroll
    for (int r = 0; r < 4; ++r) pb[(quad * 4 + r) * 16 + lrow] = f2bf(p[r]);
    bf16x8 pf, vf0, vf1;
    if (quad < 2) {
      pf = *(const bf16x8*)&pb[lrow * 16 + quad * 8];
      vf0 = *(const bf16x8*)&vtb[lrow * 16 + quad * 8];
      vf1 = *(const bf16x8*)&vtb[(16 + lrow) * 16 + quad * 8];
    } else {
#pragma unroll
      for (int j = 0; j < 8; ++j) { pf[j] = 0; vf0[j] = 0; vf1[j] = 0; }
    }
    f32x4 o0 = __builtin_amdgcn_mfma_f32_16x16x32_bf16(pf, vf0, zero4, 0, 0, 0);
    f32x4 o1 = __builtin_amdgcn_mfma_f32_16x16x32_bf16(pf, vf1, zero4, 0, 0, 0);
#pragma unroll
    for (int r = 0; r < 4; ++r) {
      int t = quad * 4 + r;
      float inv = 1.0f / rsum[r];
      qb[t * 32 + lrow] = f2bf(o0[r] * inv);
      qb[t * 32 + 16 + lrow] = f2bf(o1[r] * inv);
    }
    ao[head] = *(const bf16x8*)&qb[lrow * 32 + quad * 8];
  }
  float* ob = out + (size_t)b * kT * kC * kHW + hw0 + wave;
#pragma unroll 1
  for (int nt = 0; nt < 16; ++nt) {
    int c = nt * 16 + lrow;
    float bias = bout[c];
    f32x4 y = {bias, bias, bias, bias};
#pragma unroll
    for (int ks = 0; ks < 8; ++ks) {
      const float4 w0 = *(const float4*)(wout + (size_t)c * kC + ks * 32 + quad * 8);
      const float4 w1 = *(const float4*)(wout + (size_t)c * kC + ks * 32 + quad * 8 + 4);
      bf16x8 wf;
      wf[0] = (short)f2bf(w0.x); wf[1] = (short)f2bf(w0.y);
      wf[2] = (short)f2bf(w0.z); wf[3] = (short)f2bf(w0.w);
      wf[4] = (short)f2bf(w1.x); wf[5] = (short)f2bf(w1.y);
      wf[6] = (short)f2bf(w1.z); wf[7] = (short)f2bf(w1.w);
      y = __builtin_amdgcn_mfma_f32_16x16x32_bf16(ao[ks], wf, y, 0, 0, 0);
    }
#pragma unroll
    for (int r = 0; r < 4; ++r) {
      int t = quad * 4 + r;
      ob[(size_t)(t * kC + c) * kHW] = y[r];
    }
  }
}

}  // namespace

extern "C" void kernel_launch(void* const* d_in, const int* in_sizes, int n_in,
                              void* d_out, int out_size, void* d_ws, size_t ws_size,
                              hipStream_t stream) {
  const float* x = (const float*)d_in[0];
  const float* rel = (const float*)d_in[1];
  const float* wqkv = (const float*)d_in[2];
  const float* bqkv = (const float*)d_in[3];
  const float* wout = (const float*)d_in[4];
  const float* bout = (const float*)d_in[5];
  float* out = (float*)d_out;
  (void)in_sizes; (void)n_in; (void)out_size;

  constexpr size_t kXTElems = (size_t)4 * 1024 * 16 * 256;  // 16,777,216
  constexpr size_t kWAllElems = 1024 * 256;                 // 262,144
  constexpr size_t kNeed = (kXTElems + kWAllElems) * sizeof(unsigned short);

  if (ws_size >= kNeed) {
    unsigned short* xT = (unsigned short*)d_ws;
    unsigned short* wAll = xT + kXTElems;
    prep<<<4096 + 32, 256, 0, stream>>>(x, wqkv, wout, xT, wAll);
    attn_main<<<512, 256, 0, stream>>>(xT, rel, wAll, bqkv, bout, out);
  } else {
    fused_temporal_attn<<<1024, 256, 0, stream>>>(x, rel, wqkv, bqkv, wout, bout, out);
  }
}

// Round 4
// 254.808 us; speedup vs baseline: 1.1090x; 1.1090x over previous
//
#include <hip/hip_runtime.h>
#include <hip/hip_bf16.h>

typedef __attribute__((ext_vector_type(8))) short bf16x8;
typedef __attribute__((ext_vector_type(4))) float f32x4;

namespace {

constexpr int kT = 16;
constexpr int kC = 256;
constexpr int kHW = 1024;

__device__ __forceinline__ unsigned short f2bf(float f) {
  unsigned int x;
  __builtin_memcpy(&x, &f, 4);
  x += 0x7fff + ((x >> 16) & 1);  // round-to-nearest-even
  return (unsigned short)(x >> 16);
}
__device__ __forceinline__ unsigned int pack2(float a, float b) {
  return (unsigned int)f2bf(a) | ((unsigned int)f2bf(b) << 16);
}

// ============================ prep kernel ============================
// blocks < 4096: x (b,t,c,hw) fp32 -> xT (b,hw,t,c) bf16  (r3-proven body)
// blocks >= 4096: weight reorder+convert -> wAll bf16 [1024 rows x 256]:
//   rows g*32..g*32+31 for g<24: (head=g/3, sel=g%3) rows of wqkv;
//   g in 24..31: wout rows (g-24)*32...   (linear layout, round-0 proven)
__global__ __launch_bounds__(256) void prep(const float* __restrict__ x,
                                            const float* __restrict__ wqkv,
                                            const float* __restrict__ wout,
                                            unsigned short* __restrict__ xT,
                                            unsigned short* __restrict__ wAll) {
  __shared__ unsigned short ts[64 * 72];
  const int bx = blockIdx.x;
  const int tid = threadIdx.x;
  if (bx < 4096) {
    const int cc = bx & 3, hc = (bx >> 2) & 15, t = (bx >> 6) & 15, b = bx >> 10;
    const int c0 = cc * 64, hw0 = hc * 64;
    {
      const int ci = tid >> 2, j = tid & 3;
      const float* xrow = x + (((size_t)(b * 16 + t) * 256 + c0 + ci) * 1024) + hw0;
#pragma unroll
      for (int u = 0; u < 4; ++u) {
        const int chunk = j + u * 4;
        const float4 v = *(const float4*)(xrow + chunk * 4);
        const int hwl = chunk * 4;
        ts[(hwl + 0) * 72 + ci] = f2bf(v.x);
        ts[(hwl + 1) * 72 + ci] = f2bf(v.y);
        ts[(hwl + 2) * 72 + ci] = f2bf(v.z);
        ts[(hwl + 3) * 72 + ci] = f2bf(v.w);
      }
    }
    __syncthreads();
    {
      const int hwp = tid >> 2, jp = tid & 3;
      const uint4 a = *(const uint4*)&ts[hwp * 72 + jp * 16];
      const uint4 bq = *(const uint4*)&ts[hwp * 72 + jp * 16 + 8];
      unsigned short* dst =
          xT + ((size_t)((b * 1024 + hw0 + hwp) * 16 + t) * 256) + c0 + jp * 16;
      *(uint4*)dst = a;
      *(uint4*)(dst + 8) = bq;
    }
  } else {
    const int g = bx - 4096;            // 0..31
    const int row_l = tid >> 3;         // 0..31
    const int seg = tid & 7;            // 8 segs x 32 elems
    const float* src;
    int srow;
    if (g < 24) { src = wqkv; srow = (g % 3) * 256 + (g / 3) * 32 + row_l; }
    else        { src = wout; srow = (g - 24) * 32 + row_l; }
    const float* s = src + (size_t)srow * 256 + seg * 32;
    unsigned short* d = wAll + ((size_t)(g * 32 + row_l)) * 256 + seg * 32;
#pragma unroll
    for (int u = 0; u < 8; ++u) {
      const float4 v = *(const float4*)(s + u * 4);
      uint2 p;
      p.x = pack2(v.x, v.y);
      p.y = pack2(v.z, v.w);
      *(uint2*)(d + u * 4) = p;
    }
  }
}

// ============================ main kernel ============================
// v5: 1024 thr = 16 waves, 16 hw/block, grid 256 => 16 waves/CU (2x round-2's
// 8; rounds 1/3 proved 256-thr splits DON'T raise waves/CU and wreck the
// 64-B write path). Wave owns ONE site via m=16 16x16x32 MFMA -- index math
// lifted from the PASSING fallback kernel / round-2 site buffers.
// Weights: single-buffered 3-tile head group staged from prefetched regs
// (3 x uint4/thread): 2 barriers/head = 16 total vs round-2's 48.
constexpr int kWBStride = 264;            // 256 + 8 pad (elems)
constexpr int kWBTile = 32 * kWBStride;   // 8448 elems per tile
constexpr int kWG = 3 * kWBTile;          // 25344 elems (Q,K,V tiles of head)
constexpr int kSite = 1824;               // per-wave: q640(s40)|k640(s40,P s24)|vt512(s16)|pad
constexpr int kSmem = kWG + 16 * kSite;   // 54528 elems = 109056 B
static_assert(kSmem * 2 <= 131072, "LDS within guide-proven 128KiB envelope");
static_assert(2 * 512 * 17 * 4 <= kSmem * 2, "epilogue fbuf fits");

__global__ __launch_bounds__(1024) void attn_main(
    const unsigned short* __restrict__ xT,    // (4,1024,16,256) bf16
    const float* __restrict__ rel,            // (8,16,16) fp32
    const unsigned short* __restrict__ wAll,  // (1024,256) bf16 reordered
    const float* __restrict__ bqkv,           // (768,) fp32
    const float* __restrict__ bout,           // (256,) fp32
    float* __restrict__ out) {                // (4,16,256,32,32) fp32
  __shared__ __align__(16) unsigned short smem[kSmem];
  const int tid = threadIdx.x;
  const int lane = tid & 63;
  const int wave = tid >> 6;   // 0..15
  const int quad = lane >> 4;
  const int lrow = lane & 15;
  const int b = blockIdx.x >> 6;
  const int hw0 = (blockIdx.x & 63) * 16;
  const int site = hw0 + wave;

  // ---- A-frags of X for this wave's site: ax[ks][j] = x[site][t=lrow][c] ----
  bf16x8 ax[8];
  {
    const unsigned short* xs =
        xT + (((size_t)(b * 1024 + site)) << 12) + lrow * 256;
#pragma unroll
    for (int ks = 0; ks < 8; ++ks)
      ax[ks] = *(const bf16x8*)(xs + ks * 32 + quad * 8);
  }

  unsigned short* qb = smem + kWG + wave * kSite;
  unsigned short* kb = qb + 640;
  unsigned short* vt = qb + 1280;  // stride 16, [d][j]

  // staging: per head-group 3 tiles; thread owns (row=tid>>5, 8-elem chunk)
  const int srow = tid >> 5;          // 0..31
  const int scol = (tid & 31) * 8;    // 0..248
  const int stageDst = srow * kWBStride + scol;
  const int stageSrc = srow * 256 + scol;

  uint4 pr[3];
  {
#pragma unroll
    for (int u = 0; u < 3; ++u)
      pr[u] = *(const uint4*)(wAll + (size_t)u * 8192 + stageSrc);
  }

  const f32x4 zero4 = {0.f, 0.f, 0.f, 0.f};
  const float scale = 0.17677669529663687f;  // 32^-0.5
  bf16x8 ao[8];

  // one 16x16x32 projection chain over the staged tile selIdx (d 0..31)
  auto proj = [&](int selIdx, float bias0, float bias1, f32x4& acc0, f32x4& acc1) {
    const unsigned short* W = smem + selIdx * kWBTile;
    acc0 = f32x4{bias0, bias0, bias0, bias0};
    acc1 = f32x4{bias1, bias1, bias1, bias1};
#pragma unroll
    for (int ks = 0; ks < 8; ++ks) {
      const bf16x8 w0 = *(const bf16x8*)(W + lrow * kWBStride + ks * 32 + quad * 8);
      const bf16x8 w1 = *(const bf16x8*)(W + (16 + lrow) * kWBStride + ks * 32 + quad * 8);
      acc0 = __builtin_amdgcn_mfma_f32_16x16x32_bf16(ax[ks], w0, acc0, 0, 0, 0);
      acc1 = __builtin_amdgcn_mfma_f32_16x16x32_bf16(ax[ks], w1, acc1, 0, 0, 0);
    }
  };

  // one head, h literal at each call site (ao statically indexed -> registers)
  auto head_body = [&](int h) {
    __syncthreads();  // all waves done reading group h-1
#pragma unroll
    for (int u = 0; u < 3; ++u)
      *(uint4*)(smem + u * kWBTile + stageDst) = pr[u];
    {
      const int gn = 3 * (h + 1);  // h=7 -> tiles 24..26 (wout rows): valid mem
#pragma unroll
      for (int u = 0; u < 3; ++u)
        pr[u] = *(const uint4*)(wAll + (size_t)(gn + u) * 8192 + stageSrc);
    }
    __syncthreads();  // group h ready

    f32x4 a0, a1;
    // Q
    proj(0, bqkv[h * 32 + lrow], bqkv[h * 32 + 16 + lrow], a0, a1);
#pragma unroll
    for (int r = 0; r < 4; ++r) {
      const int t = quad * 4 + r;
      qb[t * 40 + lrow] = f2bf(a0[r]);
      qb[t * 40 + 16 + lrow] = f2bf(a1[r]);
    }
    // K
    proj(1, bqkv[256 + h * 32 + lrow], bqkv[256 + h * 32 + 16 + lrow], a0, a1);
#pragma unroll
    for (int r = 0; r < 4; ++r) {
      const int t = quad * 4 + r;
      kb[t * 40 + lrow] = f2bf(a0[r]);
      kb[t * 40 + 16 + lrow] = f2bf(a1[r]);
    }
    // V -> vt[d][j] (stride 16), paired t writes (b32)
    proj(2, bqkv[512 + h * 32 + lrow], bqkv[512 + h * 32 + 16 + lrow], a0, a1);
#pragma unroll
    for (int rp = 0; rp < 2; ++rp) {
      const int r = rp * 2;
      const int t = quad * 4 + r;
      *(unsigned int*)&vt[lrow * 16 + t] = pack2(a0[r], a0[r + 1]);
      *(unsigned int*)&vt[(16 + lrow) * 16 + t] = pack2(a1[r], a1[r + 1]);
    }

    float rl[4];
#pragma unroll
    for (int r = 0; r < 4; ++r) rl[r] = rel[h * 256 + (quad * 4 + r) * 16 + lrow];

    // sim (16x16x32): A=q[m=t][k=d], B[k=d][n=j]=k[j][d]
    const bf16x8 qf = *(const bf16x8*)(qb + lrow * 40 + quad * 8);
    const bf16x8 kf = *(const bf16x8*)(kb + lrow * 40 + quad * 8);
    const f32x4 sim = __builtin_amdgcn_mfma_f32_16x16x32_bf16(qf, kf, zero4, 0, 0, 0);
    float p[4], inv[4];
#pragma unroll
    for (int r = 0; r < 4; ++r) {
      const float v = sim[r] * scale + rl[r];
      float m = v;
      for (int off = 8; off; off >>= 1) m = fmaxf(m, __shfl_xor(m, off));
      const float e = __expf(v - m);
      float sum = e;
      for (int off = 8; off; off >>= 1) sum += __shfl_xor(sum, off);
      p[r] = e;
      inv[r] = 1.0f / sum;
    }
    unsigned short* pb = kb;  // P overlays k (dead), stride 24
#pragma unroll
    for (int r = 0; r < 4; ++r) pb[(quad * 4 + r) * 24 + lrow] = f2bf(p[r]);
    bf16x8 pf, vf0, vf1;
    if (quad < 2) {
      pf = *(const bf16x8*)(pb + lrow * 24 + quad * 8);
      vf0 = *(const bf16x8*)(vt + lrow * 16 + quad * 8);
      vf1 = *(const bf16x8*)(vt + (16 + lrow) * 16 + quad * 8);
    } else {
#pragma unroll
      for (int j = 0; j < 8; ++j) { pf[j] = 0; vf0[j] = 0; vf1[j] = 0; }
    }
    const f32x4 o0 = __builtin_amdgcn_mfma_f32_16x16x32_bf16(pf, vf0, zero4, 0, 0, 0);
    const f32x4 o1 = __builtin_amdgcn_mfma_f32_16x16x32_bf16(pf, vf1, zero4, 0, 0, 0);
#pragma unroll
    for (int r = 0; r < 4; ++r) {  // O bounce into qb (dead) -> A-layout
      const int t = quad * 4 + r;
      qb[t * 40 + lrow] = f2bf(o0[r] * inv[r]);
      qb[t * 40 + 16 + lrow] = f2bf(o1[r] * inv[r]);
    }
    ao[h] = *(const bf16x8*)(qb + lrow * 40 + quad * 8);
  };

  head_body(0);
  head_body(1);
  head_body(2);
  head_body(3);
  head_body(4);
  head_body(5);
  head_body(6);
  head_body(7);

  // ---- epilogue: y = O @ wout^T + bout; 2 c-groups per pass so all 1024
  // threads store full 64-B lines. fbuf overlays smem (all dead). ----
  __syncthreads();
  float* fbuf = (float*)smem;  // [g][ (t*32+c_l)*17 + hw_l ], g-stride 8704
  float* ob = out + ((size_t)b << 22);
#pragma unroll 1
  for (int cp = 0; cp < 4; ++cp) {
#pragma unroll
    for (int g = 0; g < 2; ++g) {
      const int cc = cp * 2 + g;
#pragma unroll
      for (int sub = 0; sub < 2; ++sub) {
        const int c = cc * 32 + sub * 16 + lrow;
        const float bias = bout[c];
        f32x4 y = {bias, bias, bias, bias};
#pragma unroll
        for (int ks = 0; ks < 8; ++ks) {
          const bf16x8 wf =
              *(const bf16x8*)(wAll + (size_t)(768 + c) * 256 + ks * 32 + quad * 8);
          y = __builtin_amdgcn_mfma_f32_16x16x32_bf16(ao[ks], wf, y, 0, 0, 0);
        }
#pragma unroll
        for (int r = 0; r < 4; ++r) {
          const int t = quad * 4 + r;
          fbuf[g * 8704 + (t * 32 + sub * 16 + lrow) * 17 + wave] = y[r];
        }
      }
    }
    __syncthreads();
    {
      const int g2 = tid >> 9, L = tid & 511;
      const int t = L >> 5, cl = L & 31;
      float v[16];
#pragma unroll
      for (int i = 0; i < 16; ++i) v[i] = fbuf[g2 * 8704 + L * 17 + i];
      float* dst = ob + ((size_t)(t * 256 + (cp * 2 + g2) * 32 + cl)) * 1024 + hw0;
#pragma unroll
      for (int u = 0; u < 4; ++u) {
        float4 q;
        q.x = v[u * 4]; q.y = v[u * 4 + 1]; q.z = v[u * 4 + 2]; q.w = v[u * 4 + 3];
        *(float4*)(dst + u * 4) = q;
      }
    }
    __syncthreads();
  }
}

// ============================ fallback (round-2, passed) ============================
constexpr int kHWT = 4;
constexpr int kXsTStride = kC * kHWT + 8;
constexpr int kXSize = kT * kXsTStride;
constexpr int kWsOff = kXSize;
constexpr int kWsStride = 264;
constexpr int kWsSize = 32 * kWsStride;
constexpr int kQbOff = kWsOff + kWsSize;
constexpr int kQbWave = 1792;
constexpr int kLdsElems = kQbOff + 4 * kQbWave;

__global__ __launch_bounds__(256, 2) void fused_temporal_attn(
    const float* __restrict__ x, const float* __restrict__ rel,
    const float* __restrict__ wqkv, const float* __restrict__ bqkv,
    const float* __restrict__ wout, const float* __restrict__ bout,
    float* __restrict__ out) {
  __shared__ __align__(16) unsigned short smem[kLdsElems];
  const int tid = threadIdx.x;
  const int lane = tid & 63;
  const int wave = tid >> 6;
  const int quad = lane >> 4;
  const int lrow = lane & 15;
  const int b = blockIdx.x >> 8;
  const int tile = blockIdx.x & 255;
  const int hw0 = tile * kHWT;
  {
    const float* xb = x + (size_t)b * kT * kC * kHW + hw0;
#pragma unroll
    for (int it = 0; it < 16; ++it) {
      int idx = it * 256 + tid;
      int t = idx >> 8, c = idx & 255;
      const float4 v = *(const float4*)(xb + (size_t)(t * kC + c) * kHW);
      uint2 p;
      p.x = pack2(v.x, v.y);
      p.y = pack2(v.z, v.w);
      *(uint2*)&smem[t * kXsTStride + c * kHWT] = p;
    }
  }
  __syncthreads();
  bf16x8 ax[8];
#pragma unroll
  for (int ks = 0; ks < 8; ++ks) {
    bf16x8 f;
#pragma unroll
    for (int j = 0; j < 8; ++j) {
      int c = ks * 32 + quad * 8 + j;
      f[j] = (short)smem[lrow * kXsTStride + c * kHWT + wave];
    }
    ax[ks] = f;
  }
  unsigned short* qb = &smem[kQbOff + wave * kQbWave];
  unsigned short* kbuf = qb + 512;
  unsigned short* vtb = qb + 1024;
  unsigned short* pb = qb + 1536;
  const f32x4 zero4 = {0.f, 0.f, 0.f, 0.f};
  bf16x8 ao[8];
  for (int head = 0; head < 8; ++head) {
    for (int sel = 0; sel < 3; ++sel) {
      __syncthreads();
      {
        const float* wbp = wqkv + (size_t)(sel * 256 + head * 32) * kC;
#pragma unroll
        for (int i = 0; i < 8; ++i) {
          int seg = i * 256 + tid;
          int d = seg >> 6, s = seg & 63;
          const float4 v = *(const float4*)(wbp + d * kC + s * 4);
          uint2 p;
          p.x = pack2(v.x, v.y);
          p.y = pack2(v.z, v.w);
          *(uint2*)&smem[kWsOff + d * kWsStride + s * 4] = p;
        }
      }
      __syncthreads();
      float bias0 = bqkv[sel * 256 + head * 32 + lrow];
      float bias1 = bqkv[sel * 256 + head * 32 + 16 + lrow];
      f32x4 acc0 = {bias0, bias0, bias0, bias0};
      f32x4 acc1 = {bias1, bias1, bias1, bias1};
#pragma unroll
      for (int ks = 0; ks < 8; ++ks) {
        bf16x8 b0 = *(const bf16x8*)&smem[kWsOff + lrow * kWsStride + ks * 32 + quad * 8];
        bf16x8 b1 = *(const bf16x8*)&smem[kWsOff + (16 + lrow) * kWsStride + ks * 32 + quad * 8];
        acc0 = __builtin_amdgcn_mfma_f32_16x16x32_bf16(ax[ks], b0, acc0, 0, 0, 0);
        acc1 = __builtin_amdgcn_mfma_f32_16x16x32_bf16(ax[ks], b1, acc1, 0, 0, 0);
      }
      if (sel < 2) {
        unsigned short* dst = sel ? kbuf : qb;
#pragma unroll
        for (int r = 0; r < 4; ++r) {
          int row = quad * 4 + r;
          dst[row * 32 + lrow] = f2bf(acc0[r]);
          dst[row * 32 + 16 + lrow] = f2bf(acc1[r]);
        }
      } else {
#pragma unroll
        for (int r = 0; r < 4; ++r) {
          int row = quad * 4 + r;
          vtb[lrow * 16 + row] = f2bf(acc0[r]);
          vtb[(16 + lrow) * 16 + row] = f2bf(acc1[r]);
        }
      }
    }
    bf16x8 qf = *(const bf16x8*)&qb[lrow * 32 + quad * 8];
    bf16x8 kf = *(const bf16x8*)&kbuf[lrow * 32 + quad * 8];
    f32x4 sim = __builtin_amdgcn_mfma_f32_16x16x32_bf16(qf, kf, zero4, 0, 0, 0);
    const float scale = 0.17677669529663687f;
    float p[4], rsum[4];
#pragma unroll
    for (int r = 0; r < 4; ++r) {
      int i = quad * 4 + r;
      float v = sim[r] * scale + rel[head * 256 + i * 16 + lrow];
      float m = v;
      for (int off = 8; off; off >>= 1) m = fmaxf(m, __shfl_xor(m, off));
      float e = __expf(v - m);
      float s = e;
      for (int off = 8; off; off >>= 1) s += __shfl_xor(s, off);
      p[r] = e;
      rsum[r] = s;
    }
#pragma unroll
    for (int r = 0; r < 4; ++r) pb[(quad * 4 + r) * 16 + lrow] = f2bf(p[r]);
    bf16x8 pf, vf0, vf1;
    if (quad < 2) {
      pf = *(const bf16x8*)&pb[lrow * 16 + quad * 8];
      vf0 = *(const bf16x8*)&vtb[lrow * 16 + quad * 8];
      vf1 = *(const bf16x8*)&vtb[(16 + lrow) * 16 + quad * 8];
    } else {
#pragma unroll
      for (int j = 0; j < 8; ++j) { pf[j] = 0; vf0[j] = 0; vf1[j] = 0; }
    }
    f32x4 o0 = __builtin_amdgcn_mfma_f32_16x16x32_bf16(pf, vf0, zero4, 0, 0, 0);
    f32x4 o1 = __builtin_amdgcn_mfma_f32_16x16x32_bf16(pf, vf1, zero4, 0, 0, 0);
#pragma unroll
    for (int r = 0; r < 4; ++r) {
      int t = quad * 4 + r;
      float inv = 1.0f / rsum[r];
      qb[t * 32 + lrow] = f2bf(o0[r] * inv);
      qb[t * 32 + 16 + lrow] = f2bf(o1[r] * inv);
    }
    ao[head] = *(const bf16x8*)&qb[lrow * 32 + quad * 8];
  }
  float* ob = out + (size_t)b * kT * kC * kHW + hw0 + wave;
#pragma unroll 1
  for (int nt = 0; nt < 16; ++nt) {
    int c = nt * 16 + lrow;
    float bias = bout[c];
    f32x4 y = {bias, bias, bias, bias};
#pragma unroll
    for (int ks = 0; ks < 8; ++ks) {
      const float4 w0 = *(const float4*)(wout + (size_t)c * kC + ks * 32 + quad * 8);
      const float4 w1 = *(const float4*)(wout + (size_t)c * kC + ks * 32 + quad * 8 + 4);
      bf16x8 wf;
      wf[0] = (short)f2bf(w0.x); wf[1] = (short)f2bf(w0.y);
      wf[2] = (short)f2bf(w0.z); wf[3] = (short)f2bf(w0.w);
      wf[4] = (short)f2bf(w1.x); wf[5] = (short)f2bf(w1.y);
      wf[6] = (short)f2bf(w1.z); wf[7] = (short)f2bf(w1.w);
      y = __builtin_amdgcn_mfma_f32_16x16x32_bf16(ao[ks], wf, y, 0, 0, 0);
    }
#pragma unroll
    for (int r = 0; r < 4; ++r) {
      int t = quad * 4 + r;
      ob[(size_t)(t * kC + c) * kHW] = y[r];
    }
  }
}

}  // namespace

extern "C" void kernel_launch(void* const* d_in, const int* in_sizes, int n_in,
                              void* d_out, int out_size, void* d_ws, size_t ws_size,
                              hipStream_t stream) {
  const float* x = (const float*)d_in[0];
  const float* rel = (const float*)d_in[1];
  const float* wqkv = (const float*)d_in[2];
  const float* bqkv = (const float*)d_in[3];
  const float* wout = (const float*)d_in[4];
  const float* bout = (const float*)d_in[5];
  float* out = (float*)d_out;
  (void)in_sizes; (void)n_in; (void)out_size;

  constexpr size_t kXTElems = (size_t)4 * 1024 * 16 * 256;  // 16,777,216
  constexpr size_t kWAllElems = 1024 * 256;                 // 262,144
  constexpr size_t kNeed = (kXTElems + kWAllElems) * sizeof(unsigned short);

  if (ws_size >= kNeed) {
    unsigned short* xT = (unsigned short*)d_ws;
    unsigned short* wAll = xT + kXTElems;
    prep<<<4096 + 32, 256, 0, stream>>>(x, wqkv, wout, xT, wAll);
    attn_main<<<256, 1024, 0, stream>>>(xT, rel, wAll, bqkv, bout, out);
  } else {
    fused_temporal_attn<<<1024, 256, 0, stream>>>(x, rel, wqkv, bqkv, wout, bout, out);
  }
}

// Round 5
// 245.507 us; speedup vs baseline: 1.1510x; 1.0379x over previous
//
#include <hip/hip_runtime.h>
#include <hip/hip_bf16.h>

typedef __attribute__((ext_vector_type(8))) short bf16x8;
typedef __attribute__((ext_vector_type(4))) float f32x4;
typedef __attribute__((ext_vector_type(16))) float f32x16;

namespace {

__device__ __forceinline__ unsigned short f2bf(float f) {
  unsigned int x;
  __builtin_memcpy(&x, &f, 4);
  x += 0x7fff + ((x >> 16) & 1);  // round-to-nearest-even
  return (unsigned short)(x >> 16);
}
__device__ __forceinline__ unsigned int pack2(float a, float b) {
  return (unsigned int)f2bf(a) | ((unsigned int)f2bf(b) << 16);
}

// ============================ fused kernel ============================
// v6: single kernel (prep eliminated). Topology/body = round-2's proven
// attn_main (106.5 us): 512 thr = 8 waves, wave = 2 hw sites (m=32 MFMA),
// block = 16 hw, grid 256; dbuf 264-stride weight staging, 2 barriers/tile,
// heads fully unrolled (ao in regs). New grafts:
//  - phase X: x fp32 -> bf16 LDS panel [t][hw][c64] (stride 72) -> ax[16],
//    4 chunks reusing the WB region before weights are live.
//  - weight tiles staged from fp32 wqkv (fallback-proven conversion) via
//    4x float4 prefetch regs.
//  - epilogue converts fp32 wout per-frag (fallback-proven).
// Deletes: prep launch, 64MB x re-read, 32MB xT write, 32MB xT read.
constexpr int kWBStride = 264;                 // 256 + 8 pad (elems)
constexpr int kWBTile = 32 * kWBStride;        // 8448 elems
constexpr int kWB = 2 * kWBTile;               // 16896 elems
constexpr int kSite = 1824;                    // per-wave: q640(s40)|k640(s40,P s24)|vt512(s16)|pad
constexpr int kSmem = kWB + 8 * kSite;         // 31488 elems = 62976 B
constexpr int kPanelStride = 72;               // (t,hw) row stride; 144B: 16B-aligned b128 reads
static_assert(kSmem * 2 <= 65536, "LDS budget");
static_assert(16 * 16 * kPanelStride <= kSmem, "x panel fits");
static_assert(512 * 17 * 4 <= kSmem * 2, "fbuf fits");

__global__ __launch_bounds__(512, 2) void attn_fused(
    const float* __restrict__ x,     // (4,16,256,32,32) fp32
    const float* __restrict__ rel,   // (8,16,16) fp32
    const float* __restrict__ wqkv,  // (768,256) fp32
    const float* __restrict__ bqkv,  // (768,) fp32
    const float* __restrict__ wout,  // (256,256) fp32
    const float* __restrict__ bout,  // (256,) fp32
    float* __restrict__ out) {       // (4,16,256,32,32) fp32
  __shared__ __align__(16) unsigned short smem[kSmem];
  const int tid = threadIdx.x;
  const int lane = tid & 63;
  const int wave = tid >> 6;
  const int quad = lane >> 4;
  const int lrow = lane & 15;
  const int half = lane >> 5;
  const int n32 = lane & 31;
  const int b = blockIdx.x >> 6;
  const int hw0 = (blockIdx.x & 63) * 16;

  // ---- weight staging ids + early prefetch of QKV tile 0 (fp32) ----
  // tile g rows = wqkv rows (g%3)*256 + (g/3)*32 .. +32 (valid for g<=24)
  const int wrow = tid >> 4;         // 0..31
  const int wcol = (tid & 15) * 16;  // 0..240
  float4 pw[4];
  {
    const float* sp = wqkv + (size_t)wrow * 256 + wcol;  // rowbase(0)=0
#pragma unroll
    for (int u = 0; u < 4; ++u) pw[u] = *(const float4*)(sp + u * 4);
  }

  // ---- phase X: stage x into bf16 panel, extract A-frags ----
  // ax semantics (R2-identical): A[m=n32][k=ks*16+half*8+j] =
  //   x_bf16[b][t=lrow][c=k][hw = hw0 + 2*wave + (n32>>4)]
  bf16x8 ax[16];
  {
    unsigned short* panel = smem;
    const int sloc = wave * 2 + (n32 >> 4);
#pragma unroll
    for (int cc4 = 0; cc4 < 4; ++cc4) {  // full unroll: ax statically indexed
      const int c0 = cc4 * 64;
      __syncthreads();  // panel free (prev chunk's readers done)
#pragma unroll
      for (int u = 0; u < 8; ++u) {
        const int idx = u * 512 + tid;
        const int row = idx >> 2;  // t*64 + cl
        const int q = idx & 3;     // which 4-hw chunk
        const int t = row >> 6;
        const int cl = row & 63;
        const float4 v = *(const float4*)(
            x + (((size_t)(b * 16 + t) * 256 + c0 + cl) << 10) + hw0 + q * 4);
        unsigned short* pr = panel + (t * 16 + q * 4) * kPanelStride + cl;
        pr[0] = f2bf(v.x);
        pr[kPanelStride] = f2bf(v.y);
        pr[2 * kPanelStride] = f2bf(v.z);
        pr[3 * kPanelStride] = f2bf(v.w);
      }
      __syncthreads();  // panel ready
#pragma unroll
      for (int kk = 0; kk < 4; ++kk)
        ax[cc4 * 4 + kk] = *(const bf16x8*)(
            panel + (lrow * 16 + sloc) * kPanelStride + kk * 16 + half * 8);
    }
  }
  // qkv_tile(0)'s first barrier protects panel region before WB0 writes.

  unsigned short* qb = smem + kWB + wave * kSite;
  unsigned short* kb = qb + 640;
  unsigned short* vt = qb + 1280;  // stride 16, [d][j]

  const f32x4 zero4 = {0.f, 0.f, 0.f, 0.f};
  const float scale = 0.17677669529663687f;  // 32^-0.5
  bf16x8 ao[2][8];

  // staged QKV tile: write pw -> WB[g&1] (bf16), prefetch tile g+1 (fp32),
  // 16-kstep 32x32x16 MFMA. Barrier structure identical to R2.
  auto qkv_tile = [&](int g, float bias) -> f32x16 {
    __syncthreads();  // WB[g&1] free (consumers of g-2 done)
    unsigned short* WBc = smem + (g & 1) * kWBTile;
    {
      unsigned short* dst = WBc + wrow * kWBStride + wcol;
      uint4 a, bq;
      a.x = pack2(pw[0].x, pw[0].y);
      a.y = pack2(pw[0].z, pw[0].w);
      a.z = pack2(pw[1].x, pw[1].y);
      a.w = pack2(pw[1].z, pw[1].w);
      bq.x = pack2(pw[2].x, pw[2].y);
      bq.y = pack2(pw[2].z, pw[2].w);
      bq.z = pack2(pw[3].x, pw[3].y);
      bq.w = pack2(pw[3].z, pw[3].w);
      *(uint4*)dst = a;
      *(uint4*)(dst + 8) = bq;
    }
    {
      const int gn = g + 1;  // gn==24 -> rows 256..287: valid wqkv memory
      const int rowbase = (gn % 3) * 256 + (gn / 3) * 32;
      const float* sp = wqkv + (size_t)(rowbase + wrow) * 256 + wcol;
#pragma unroll
      for (int u = 0; u < 4; ++u) pw[u] = *(const float4*)(sp + u * 4);
    }
    __syncthreads();  // WB[g&1] ready
    f32x16 acc;
#pragma unroll
    for (int i = 0; i < 16; ++i) acc[i] = bias;
    const unsigned short* br = WBc + n32 * kWBStride + half * 8;
#pragma unroll
    for (int ks = 0; ks < 16; ++ks) {
      const bf16x8 bf = *(const bf16x8*)(br + ks * 16);
      acc = __builtin_amdgcn_mfma_f32_32x32x16_bf16(ax[ks], bf, acc, 0, 0, 0);
    }
    return acc;
  };

  // one head, h literal at each call site (R2-identical body)
  auto head_body = [&](int h) {
    const f32x16 qacc = qkv_tile(h * 3 + 0, bqkv[h * 32 + n32]);
    const f32x16 kacc = qkv_tile(h * 3 + 1, bqkv[256 + h * 32 + n32]);
    const f32x16 vacc = qkv_tile(h * 3 + 2, bqkv[512 + h * 32 + n32]);
    float rl[4];
#pragma unroll
    for (int r = 0; r < 4; ++r) rl[r] = rel[h * 256 + (quad * 4 + r) * 16 + lrow];

#pragma unroll
    for (int s = 0; s < 2; ++s) {
      // C/D 32x32: reg=8s+rr -> row=16s+t, t=(rr&3)+8*(rr>>2)+4*half, col=n32
#pragma unroll
      for (int rr = 0; rr < 8; ++rr) {
        const int t = (rr & 3) + 8 * (rr >> 2) + 4 * half;
        qb[t * 40 + n32] = f2bf(qacc[8 * s + rr]);
        kb[t * 40 + n32] = f2bf(kacc[8 * s + rr]);
      }
#pragma unroll
      for (int rp = 0; rp < 4; ++rp) {  // vT[d][j], paired t writes (b32)
        const int rr = rp * 2;
        const int t = (rr & 3) + 8 * (rr >> 2) + 4 * half;
        *(unsigned int*)&vt[n32 * 16 + t] =
            pack2(vacc[8 * s + rr], vacc[8 * s + rr + 1]);
      }
      // sim (16x16x32): A=q[m=t][k=d], B[k=d][n=j]=k[j][d]
      const bf16x8 qf = *(const bf16x8*)(qb + lrow * 40 + quad * 8);
      const bf16x8 kf = *(const bf16x8*)(kb + lrow * 40 + quad * 8);
      const f32x4 sim = __builtin_amdgcn_mfma_f32_16x16x32_bf16(qf, kf, zero4, 0, 0, 0);
      float p[4], inv[4];
#pragma unroll
      for (int r = 0; r < 4; ++r) {
        const float v = sim[r] * scale + rl[r];
        float m = v;
        for (int off = 8; off; off >>= 1) m = fmaxf(m, __shfl_xor(m, off));
        const float e = __expf(v - m);
        float sum = e;
        for (int off = 8; off; off >>= 1) sum += __shfl_xor(sum, off);
        p[r] = e;
        inv[r] = 1.0f / sum;
      }
      unsigned short* pb = kb;  // P overlays k (dead), stride 24
#pragma unroll
      for (int r = 0; r < 4; ++r) pb[(quad * 4 + r) * 24 + lrow] = f2bf(p[r]);
      bf16x8 pf, vf0, vf1;
      if (quad < 2) {
        pf = *(const bf16x8*)(pb + lrow * 24 + quad * 8);
        vf0 = *(const bf16x8*)(vt + lrow * 16 + quad * 8);
        vf1 = *(const bf16x8*)(vt + (16 + lrow) * 16 + quad * 8);
      } else {
#pragma unroll
        for (int j = 0; j < 8; ++j) { pf[j] = 0; vf0[j] = 0; vf1[j] = 0; }
      }
      const f32x4 o0 = __builtin_amdgcn_mfma_f32_16x16x32_bf16(pf, vf0, zero4, 0, 0, 0);
      const f32x4 o1 = __builtin_amdgcn_mfma_f32_16x16x32_bf16(pf, vf1, zero4, 0, 0, 0);
#pragma unroll
      for (int r = 0; r < 4; ++r) {  // O bounce into qb (dead) -> A-layout
        const int t = quad * 4 + r;
        qb[t * 40 + lrow] = f2bf(o0[r] * inv[r]);
        qb[t * 40 + 16 + lrow] = f2bf(o1[r] * inv[r]);
      }
      ao[s][h] = *(const bf16x8*)(qb + lrow * 40 + quad * 8);
    }
  };

  // fully unrolled heads: literal h -> ao[][] statically indexed (registers)
  head_body(0);
  head_body(1);
  head_body(2);
  head_body(3);
  head_body(4);
  head_body(5);
  head_body(6);
  head_body(7);

  // ---- epilogue: y = O @ wout^T + bout; wout converted per-frag from fp32
  // (fallback-proven); fbuf/store path byte-identical to R2. ----
  __syncthreads();  // sitebufs/WB dead; fbuf overlays smem
  float* fbuf = (float*)smem;  // [t*32+c_l]*17 + hw_l  (512 lines x 17)
  float* ob = out + ((size_t)b << 22);
#pragma unroll 1
  for (int cc = 0; cc < 8; ++cc) {
#pragma unroll
    for (int sub = 0; sub < 2; ++sub) {
      const int c = cc * 32 + sub * 16 + lrow;
      const float bias = bout[c];
      f32x4 y0 = {bias, bias, bias, bias};
      f32x4 y1 = {bias, bias, bias, bias};
#pragma unroll
      for (int ks = 0; ks < 8; ++ks) {
        const float4 w0 = *(const float4*)(wout + (size_t)c * 256 + ks * 32 + quad * 8);
        const float4 w1 = *(const float4*)(wout + (size_t)c * 256 + ks * 32 + quad * 8 + 4);
        bf16x8 wf;
        wf[0] = (short)f2bf(w0.x); wf[1] = (short)f2bf(w0.y);
        wf[2] = (short)f2bf(w0.z); wf[3] = (short)f2bf(w0.w);
        wf[4] = (short)f2bf(w1.x); wf[5] = (short)f2bf(w1.y);
        wf[6] = (short)f2bf(w1.z); wf[7] = (short)f2bf(w1.w);
        y0 = __builtin_amdgcn_mfma_f32_16x16x32_bf16(ao[0][ks], wf, y0, 0, 0, 0);
        y1 = __builtin_amdgcn_mfma_f32_16x16x32_bf16(ao[1][ks], wf, y1, 0, 0, 0);
      }
#pragma unroll
      for (int r = 0; r < 4; ++r) {
        const int t = quad * 4 + r;
        const int L = (t * 32 + sub * 16 + lrow) * 17 + wave * 2;
        fbuf[L] = y0[r];
        fbuf[L + 1] = y1[r];
      }
    }
    __syncthreads();
    {
      const int t = tid >> 5, cl = tid & 31;
      float v[16];
#pragma unroll
      for (int i = 0; i < 16; ++i) v[i] = fbuf[tid * 17 + i];
      float* dst = ob + ((size_t)(t * 256 + cc * 32 + cl)) * 1024 + hw0;
#pragma unroll
      for (int u = 0; u < 4; ++u) {
        float4 q;
        q.x = v[u * 4]; q.y = v[u * 4 + 1]; q.z = v[u * 4 + 2]; q.w = v[u * 4 + 3];
        *(float4*)(dst + u * 4) = q;
      }
    }
    __syncthreads();
  }
}

}  // namespace

extern "C" void kernel_launch(void* const* d_in, const int* in_sizes, int n_in,
                              void* d_out, int out_size, void* d_ws, size_t ws_size,
                              hipStream_t stream) {
  const float* x = (const float*)d_in[0];
  const float* rel = (const float*)d_in[1];
  const float* wqkv = (const float*)d_in[2];
  const float* bqkv = (const float*)d_in[3];
  const float* wout = (const float*)d_in[4];
  const float* bout = (const float*)d_in[5];
  float* out = (float*)d_out;
  (void)in_sizes; (void)n_in; (void)out_size; (void)d_ws; (void)ws_size;

  attn_fused<<<256, 512, 0, stream>>>(x, rel, wqkv, bqkv, wout, bout, out);
}

// Round 6
// 196.942 us; speedup vs baseline: 1.4349x; 1.2466x over previous
//
#include <hip/hip_runtime.h>
#include <hip/hip_bf16.h>

typedef __attribute__((ext_vector_type(8))) short bf16x8;
typedef __attribute__((ext_vector_type(4))) float f32x4;
typedef __attribute__((ext_vector_type(16))) float f32x16;

namespace {

__device__ __forceinline__ unsigned short f2bf(float f) {
  unsigned int x;
  __builtin_memcpy(&x, &f, 4);
  x += 0x7fff + ((x >> 16) & 1);  // round-to-nearest-even
  return (unsigned short)(x >> 16);
}
__device__ __forceinline__ unsigned int pack2(float a, float b) {
  return (unsigned int)f2bf(a) | ((unsigned int)f2bf(b) << 16);
}

// ============================ fused kernel ============================
// v7 = v6 with two fixes isolated from the R5 post-mortem:
//  (a) __launch_bounds__(512, 1): grid=256 is always 1 block/CU, but the
//      old (512,2) empirically capped VGPRs at 128 (R1/R2/R5 all pinned at
//      120-128) while live state is ~200 (ax 64 + ao 64 + pw 16 + accs 48)
//      -> scratch spills on the critical path. Cap 256 removes them at zero
//      occupancy cost.
//  (b) epilogue stages each 32x256 wout tile to LDS bf16 ONCE per cc
//      (16 f2bf/thread) instead of every wave converting the same rows
//      inline (128 f2bf/thread/cc, 8x duplicated): cuts ~1000 f2bf/thread
//      and 8x the wout L2 traffic.
// Everything else byte-identical to v6 (R5).
constexpr int kWBStride = 264;                 // 256 + 8 pad (elems)
constexpr int kWBTile = 32 * kWBStride;        // 8448 elems
constexpr int kWB = 2 * kWBTile;               // 16896 elems
constexpr int kSite = 1824;                    // per-wave: q640(s40)|k640(s40,P s24)|vt512(s16)|pad
constexpr int kSmem = kWB + 8 * kSite;         // 31488 elems = 62976 B
constexpr int kPanelStride = 72;               // (t,hw) row stride; 144B: 16B-aligned b128 reads
constexpr int kWTileOff = 17408;               // shorts; after fbuf (512*17 floats)
static_assert(kSmem * 2 <= 65536, "LDS budget");
static_assert(16 * 16 * kPanelStride <= kSmem, "x panel fits");
static_assert(kWTileOff + kWBTile <= kSmem, "wout tile fits after fbuf");

__global__ __launch_bounds__(512, 1) void attn_fused(
    const float* __restrict__ x,     // (4,16,256,32,32) fp32
    const float* __restrict__ rel,   // (8,16,16) fp32
    const float* __restrict__ wqkv,  // (768,256) fp32
    const float* __restrict__ bqkv,  // (768,) fp32
    const float* __restrict__ wout,  // (256,256) fp32
    const float* __restrict__ bout,  // (256,) fp32
    float* __restrict__ out) {       // (4,16,256,32,32) fp32
  __shared__ __align__(16) unsigned short smem[kSmem];
  const int tid = threadIdx.x;
  const int lane = tid & 63;
  const int wave = tid >> 6;
  const int quad = lane >> 4;
  const int lrow = lane & 15;
  const int half = lane >> 5;
  const int n32 = lane & 31;
  const int b = blockIdx.x >> 6;
  const int hw0 = (blockIdx.x & 63) * 16;

  // ---- weight staging ids + early prefetch of QKV tile 0 (fp32) ----
  // tile g rows = wqkv rows (g%3)*256 + (g/3)*32 .. +32 (valid for g<=24)
  const int wrow = tid >> 4;         // 0..31
  const int wcol = (tid & 15) * 16;  // 0..240
  float4 pw[4];
  {
    const float* sp = wqkv + (size_t)wrow * 256 + wcol;  // rowbase(0)=0
#pragma unroll
    for (int u = 0; u < 4; ++u) pw[u] = *(const float4*)(sp + u * 4);
  }

  // ---- phase X: stage x into bf16 panel, extract A-frags ----
  // ax semantics (R2-identical): A[m=n32][k=ks*16+half*8+j] =
  //   x_bf16[b][t=lrow][c=k][hw = hw0 + 2*wave + (n32>>4)]
  bf16x8 ax[16];
  {
    unsigned short* panel = smem;
    const int sloc = wave * 2 + (n32 >> 4);
#pragma unroll
    for (int cc4 = 0; cc4 < 4; ++cc4) {  // full unroll: ax statically indexed
      const int c0 = cc4 * 64;
      __syncthreads();  // panel free (prev chunk's readers done)
#pragma unroll
      for (int u = 0; u < 8; ++u) {
        const int idx = u * 512 + tid;
        const int row = idx >> 2;  // t*64 + cl
        const int q = idx & 3;     // which 4-hw chunk
        const int t = row >> 6;
        const int cl = row & 63;
        const float4 v = *(const float4*)(
            x + (((size_t)(b * 16 + t) * 256 + c0 + cl) << 10) + hw0 + q * 4);
        unsigned short* pr = panel + (t * 16 + q * 4) * kPanelStride + cl;
        pr[0] = f2bf(v.x);
        pr[kPanelStride] = f2bf(v.y);
        pr[2 * kPanelStride] = f2bf(v.z);
        pr[3 * kPanelStride] = f2bf(v.w);
      }
      __syncthreads();  // panel ready
#pragma unroll
      for (int kk = 0; kk < 4; ++kk)
        ax[cc4 * 4 + kk] = *(const bf16x8*)(
            panel + (lrow * 16 + sloc) * kPanelStride + kk * 16 + half * 8);
    }
  }
  // qkv_tile(0)'s first barrier protects panel region before WB0 writes.

  unsigned short* qb = smem + kWB + wave * kSite;
  unsigned short* kb = qb + 640;
  unsigned short* vt = qb + 1280;  // stride 16, [d][j]

  const f32x4 zero4 = {0.f, 0.f, 0.f, 0.f};
  const float scale = 0.17677669529663687f;  // 32^-0.5
  bf16x8 ao[2][8];

  // staged QKV tile: write pw -> WB[g&1] (bf16), prefetch tile g+1 (fp32),
  // 16-kstep 32x32x16 MFMA. Barrier structure identical to R2.
  auto qkv_tile = [&](int g, float bias) -> f32x16 {
    __syncthreads();  // WB[g&1] free (consumers of g-2 done)
    unsigned short* WBc = smem + (g & 1) * kWBTile;
    {
      unsigned short* dst = WBc + wrow * kWBStride + wcol;
      uint4 a, bq;
      a.x = pack2(pw[0].x, pw[0].y);
      a.y = pack2(pw[0].z, pw[0].w);
      a.z = pack2(pw[1].x, pw[1].y);
      a.w = pack2(pw[1].z, pw[1].w);
      bq.x = pack2(pw[2].x, pw[2].y);
      bq.y = pack2(pw[2].z, pw[2].w);
      bq.z = pack2(pw[3].x, pw[3].y);
      bq.w = pack2(pw[3].z, pw[3].w);
      *(uint4*)dst = a;
      *(uint4*)(dst + 8) = bq;
    }
    {
      const int gn = g + 1;  // gn==24 -> rows 256..287: valid wqkv memory
      const int rowbase = (gn % 3) * 256 + (gn / 3) * 32;
      const float* sp = wqkv + (size_t)(rowbase + wrow) * 256 + wcol;
#pragma unroll
      for (int u = 0; u < 4; ++u) pw[u] = *(const float4*)(sp + u * 4);
    }
    __syncthreads();  // WB[g&1] ready
    f32x16 acc;
#pragma unroll
    for (int i = 0; i < 16; ++i) acc[i] = bias;
    const unsigned short* br = WBc + n32 * kWBStride + half * 8;
#pragma unroll
    for (int ks = 0; ks < 16; ++ks) {
      const bf16x8 bf = *(const bf16x8*)(br + ks * 16);
      acc = __builtin_amdgcn_mfma_f32_32x32x16_bf16(ax[ks], bf, acc, 0, 0, 0);
    }
    return acc;
  };

  // one head, h literal at each call site (R2-identical body)
  auto head_body = [&](int h) {
    const f32x16 qacc = qkv_tile(h * 3 + 0, bqkv[h * 32 + n32]);
    const f32x16 kacc = qkv_tile(h * 3 + 1, bqkv[256 + h * 32 + n32]);
    const f32x16 vacc = qkv_tile(h * 3 + 2, bqkv[512 + h * 32 + n32]);
    float rl[4];
#pragma unroll
    for (int r = 0; r < 4; ++r) rl[r] = rel[h * 256 + (quad * 4 + r) * 16 + lrow];

#pragma unroll
    for (int s = 0; s < 2; ++s) {
      // C/D 32x32: reg=8s+rr -> row=16s+t, t=(rr&3)+8*(rr>>2)+4*half, col=n32
#pragma unroll
      for (int rr = 0; rr < 8; ++rr) {
        const int t = (rr & 3) + 8 * (rr >> 2) + 4 * half;
        qb[t * 40 + n32] = f2bf(qacc[8 * s + rr]);
        kb[t * 40 + n32] = f2bf(kacc[8 * s + rr]);
      }
#pragma unroll
      for (int rp = 0; rp < 4; ++rp) {  // vT[d][j], paired t writes (b32)
        const int rr = rp * 2;
        const int t = (rr & 3) + 8 * (rr >> 2) + 4 * half;
        *(unsigned int*)&vt[n32 * 16 + t] =
            pack2(vacc[8 * s + rr], vacc[8 * s + rr + 1]);
      }
      // sim (16x16x32): A=q[m=t][k=d], B[k=d][n=j]=k[j][d]
      const bf16x8 qf = *(const bf16x8*)(qb + lrow * 40 + quad * 8);
      const bf16x8 kf = *(const bf16x8*)(kb + lrow * 40 + quad * 8);
      const f32x4 sim = __builtin_amdgcn_mfma_f32_16x16x32_bf16(qf, kf, zero4, 0, 0, 0);
      float p[4], inv[4];
#pragma unroll
      for (int r = 0; r < 4; ++r) {
        const float v = sim[r] * scale + rl[r];
        float m = v;
        for (int off = 8; off; off >>= 1) m = fmaxf(m, __shfl_xor(m, off));
        const float e = __expf(v - m);
        float sum = e;
        for (int off = 8; off; off >>= 1) sum += __shfl_xor(sum, off);
        p[r] = e;
        inv[r] = 1.0f / sum;
      }
      unsigned short* pb = kb;  // P overlays k (dead), stride 24
#pragma unroll
      for (int r = 0; r < 4; ++r) pb[(quad * 4 + r) * 24 + lrow] = f2bf(p[r]);
      bf16x8 pf, vf0, vf1;
      if (quad < 2) {
        pf = *(const bf16x8*)(pb + lrow * 24 + quad * 8);
        vf0 = *(const bf16x8*)(vt + lrow * 16 + quad * 8);
        vf1 = *(const bf16x8*)(vt + (16 + lrow) * 16 + quad * 8);
      } else {
#pragma unroll
        for (int j = 0; j < 8; ++j) { pf[j] = 0; vf0[j] = 0; vf1[j] = 0; }
      }
      const f32x4 o0 = __builtin_amdgcn_mfma_f32_16x16x32_bf16(pf, vf0, zero4, 0, 0, 0);
      const f32x4 o1 = __builtin_amdgcn_mfma_f32_16x16x32_bf16(pf, vf1, zero4, 0, 0, 0);
#pragma unroll
      for (int r = 0; r < 4; ++r) {  // O bounce into qb (dead) -> A-layout
        const int t = quad * 4 + r;
        qb[t * 40 + lrow] = f2bf(o0[r] * inv[r]);
        qb[t * 40 + 16 + lrow] = f2bf(o1[r] * inv[r]);
      }
      ao[s][h] = *(const bf16x8*)(qb + lrow * 40 + quad * 8);
    }
  };

  // fully unrolled heads: literal h -> ao[][] statically indexed (registers)
  head_body(0);
  head_body(1);
  head_body(2);
  head_body(3);
  head_body(4);
  head_body(5);
  head_body(6);
  head_body(7);

  // ---- epilogue: y = O @ wout^T + bout ----
  // Per cc: stage wout rows cc*32..+32 once to LDS bf16 (16 f2bf/thread,
  // shared by all 8 waves), MFMA reads b128 from padded tile, fbuf bounce,
  // 64-B coalesced stores (R2-proven path).
  __syncthreads();  // sitebufs/WB dead; fbuf+wtile overlay smem
  float* fbuf = (float*)smem;                 // 512 lines x 17 floats
  unsigned short* wtile = smem + kWTileOff;   // 32 x 264 bf16
  float* ob = out + ((size_t)b << 22);
#pragma unroll 1
  for (int cc = 0; cc < 8; ++cc) {
    {
      const float* sp = wout + (size_t)(cc * 32 + wrow) * 256 + wcol;
      float4 v0 = ((const float4*)sp)[0];
      float4 v1 = ((const float4*)sp)[1];
      float4 v2 = ((const float4*)sp)[2];
      float4 v3 = ((const float4*)sp)[3];
      uint4 a, bq;
      a.x = pack2(v0.x, v0.y);
      a.y = pack2(v0.z, v0.w);
      a.z = pack2(v1.x, v1.y);
      a.w = pack2(v1.z, v1.w);
      bq.x = pack2(v2.x, v2.y);
      bq.y = pack2(v2.z, v2.w);
      bq.z = pack2(v3.x, v3.y);
      bq.w = pack2(v3.z, v3.w);
      unsigned short* d = wtile + wrow * kWBStride + wcol;
      *(uint4*)d = a;
      *(uint4*)(d + 8) = bq;
    }
    __syncthreads();  // wtile ready
#pragma unroll
    for (int sub = 0; sub < 2; ++sub) {
      const int c = cc * 32 + sub * 16 + lrow;
      const float bias = bout[c];
      f32x4 y0 = {bias, bias, bias, bias};
      f32x4 y1 = {bias, bias, bias, bias};
      const unsigned short* wrow_p = wtile + (sub * 16 + lrow) * kWBStride;
#pragma unroll
      for (int ks = 0; ks < 8; ++ks) {
        const bf16x8 wf = *(const bf16x8*)(wrow_p + ks * 32 + quad * 8);
        y0 = __builtin_amdgcn_mfma_f32_16x16x32_bf16(ao[0][ks], wf, y0, 0, 0, 0);
        y1 = __builtin_amdgcn_mfma_f32_16x16x32_bf16(ao[1][ks], wf, y1, 0, 0, 0);
      }
#pragma unroll
      for (int r = 0; r < 4; ++r) {
        const int t = quad * 4 + r;
        const int L = (t * 32 + sub * 16 + lrow) * 17 + wave * 2;
        fbuf[L] = y0[r];
        fbuf[L + 1] = y1[r];
      }
    }
    __syncthreads();
    {
      const int t = tid >> 5, cl = tid & 31;
      float v[16];
#pragma unroll
      for (int i = 0; i < 16; ++i) v[i] = fbuf[tid * 17 + i];
      float* dst = ob + ((size_t)(t * 256 + cc * 32 + cl)) * 1024 + hw0;
#pragma unroll
      for (int u = 0; u < 4; ++u) {
        float4 q;
        q.x = v[u * 4]; q.y = v[u * 4 + 1]; q.z = v[u * 4 + 2]; q.w = v[u * 4 + 3];
        *(float4*)(dst + u * 4) = q;
      }
    }
    __syncthreads();  // fbuf+wtile free for next cc
  }
}

}  // namespace

extern "C" void kernel_launch(void* const* d_in, const int* in_sizes, int n_in,
                              void* d_out, int out_size, void* d_ws, size_t ws_size,
                              hipStream_t stream) {
  const float* x = (const float*)d_in[0];
  const float* rel = (const float*)d_in[1];
  const float* wqkv = (const float*)d_in[2];
  const float* bqkv = (const float*)d_in[3];
  const float* wout = (const float*)d_in[4];
  const float* bout = (const float*)d_in[5];
  float* out = (float*)d_out;
  (void)in_sizes; (void)n_in; (void)out_size; (void)d_ws; (void)ws_size;

  attn_fused<<<256, 512, 0, stream>>>(x, rel, wqkv, bqkv, wout, bout, out);
}